// Round 10
// baseline (137.022 us; speedup 1.0000x reference)
//
#include <hip/hip_runtime.h>

// SoftProjection: B=4, N=8192 points, M=4096 queries, F=64 features, K=16 NN.
// R12: pass-B QPW=8. R11 (118.9us total / 57.2us main, VALUBusy 72%) static
// split: pair-math VALU ~13us, LDS-read port ~20us (128 ds_read_b128/lane;
// 64B group-load serves only 16 pair-evals at QPW=4). Pass A needs the
// wave-pair half-split for the threshold proof; pass B does not (all 32
// thresholds are in s_thr). So pass B only: wave = (octet = wave>>2 -> 8
// queries) x (quarter = wave&3 of each chunk, ob = qtr*512 + lane*4).
// Each 4-pt group-load now serves 32 pair-evals: pass-B LDS reads and
// addressing halved. VAL chain bit-identical (same fmaf expr, same staged
// inputs, -2.0f*q recomputed identically) => survivor set unchanged.
// Register envelope = R0's QPW=8 scan (44 VGPR measured) -> expect ~50.
// Rest identical to R11 (validated): pass A QPW=4 wave-pairs, 16-iter radix
// 8th-per-half, t=max(halves) >= 16 pts; exact (val,idx) rank; wave-parallel
// exact direct-form d2 epilogue. 512 blocks x 1024 thr, LDS 49KB, 2 blk/CU.

#define BB 4
#define NN 8192
#define MM 4096
#define FF 64
#define KK 16
#define CHUNK 2048
#define NCHUNK 4
#define QPW 4
#define QPB 32
#define SCAP 54
#define NTHR 1024
#define STG 33

__device__ __forceinline__ float min3f(float a, float b, float c) {
    float d;
    asm("v_min3_f32 %0, %1, %2, %3" : "=v"(d) : "v"(a), "v"(b), "v"(c));
    return d;
}

__global__ __launch_bounds__(256) void transpose_feat(const float* __restrict__ pf,
                                                      float* __restrict__ pfT) {
    __shared__ float tile[64][65];
    const int b = blockIdx.y;
    const int n0 = blockIdx.x * 64;
    const int t = threadIdx.x;
    const int n = t & 63, fq = t >> 6;
#pragma unroll
    for (int i = 0; i < 16; ++i) {
        int f = fq * 16 + i;
        tile[f][n] = pf[(size_t)b * FF * NN + (size_t)f * NN + n0 + n];
    }
    __syncthreads();
    const int f2 = t & 63, nq = t >> 6;
#pragma unroll
    for (int i = 0; i < 16; ++i) {
        int nn2 = nq * 16 + i;
        pfT[(size_t)b * NN * FF + (size_t)(n0 + nn2) * FF + f2] = tile[f2][nn2];
    }
}

__device__ __forceinline__ unsigned mapf(float f) {
    unsigned u = __float_as_uint(f);
    return (u & 0x80000000u) ? ~u : (u | 0x80000000u);
}
__device__ __forceinline__ float unmapf(unsigned k) {
    return (k & 0x80000000u) ? __uint_as_float(k ^ 0x80000000u)
                             : __uint_as_float(~k);
}

// stage chunk C of point cloud into LDS: x, y, z, ps=|p|^2 (512 stager threads)
#define STAGE(C)                                                            \
    do {                                                                    \
        if (t < CHUNK / 4) {                                                \
            int base_ = (C)*CHUNK + t * 4;                                  \
            float4 x4_ = *(const float4*)(pcb + base_);                     \
            float4 y4_ = *(const float4*)(pcb + NN + base_);                \
            float4 z4_ = *(const float4*)(pcb + 2 * NN + base_);            \
            *(float4*)(s_pts + t * 4) = x4_;                                \
            *(float4*)(s_pts + CHUNK + t * 4) = y4_;                        \
            *(float4*)(s_pts + 2 * CHUNK + t * 4) = z4_;                    \
            float4 p4_;                                                     \
            p4_.x = fmaf(x4_.x, x4_.x, fmaf(y4_.x, y4_.x, z4_.x * z4_.x));  \
            p4_.y = fmaf(x4_.y, x4_.y, fmaf(y4_.y, y4_.y, z4_.y * z4_.y));  \
            p4_.z = fmaf(x4_.z, x4_.z, fmaf(y4_.z, y4_.z, z4_.z * z4_.z));  \
            p4_.w = fmaf(x4_.w, x4_.w, fmaf(y4_.w, y4_.w, z4_.w * z4_.w));  \
            *(float4*)(s_pts + 3 * CHUNK + t * 4) = p4_;                    \
        }                                                                   \
    } while (0)

// identical val expression in both passes (explicit fmaf => bit-deterministic)
#define VAL(X, Y, Z, PS, QX, QY, QZ) \
    fmaf((X), (QX), fmaf((Y), (QY), fmaf((Z), (QZ), (PS))))

#define PUSH(WQ, V, I)                                          \
    do {                                                        \
        int pos_ = atomicAdd(&s_cnt[WQ], 1);                    \
        if (pos_ < SCAP) {                                      \
            s_surv[((WQ)*SCAP + pos_) * 2] = (V);               \
            s_surv[((WQ)*SCAP + pos_) * 2 + 1] = __int_as_float(I); \
        }                                                       \
    } while (0)

__global__ __launch_bounds__(NTHR, 8) void soft_proj_kernel(
    const float* __restrict__ pc, const float* __restrict__ qc,
    const float* __restrict__ pf, const float* __restrict__ pfT,
    const float* __restrict__ temp, float* __restrict__ out, int useT) {
    __shared__ __align__(16) float s_pts[4 * CHUNK];        // 32768 B
    __shared__ __align__(16) float s_surv[QPB * SCAP * 2];  // 13824 B (val,idx)
    __shared__ int s_cnt[QPB];                              // 128 B
    __shared__ int s_sel[QPB * KK];                         // 2048 B
    __shared__ float s_thr[2 * QPB];                        // 256 B => 49024 B

    const int bid = blockIdx.x;
    const int b = bid >> 7;               // 128 blocks per batch
    const int m0 = (bid & 127) * QPB;
    const int t = threadIdx.x;
    const int wave = t >> 6;              // 16 waves
    const int lane = t & 63;
    const int pairIdx = wave & 7;         // 8 wave-pairs x QPW=4 queries = 32
    const int half = wave >> 3;           // which point-half this wave scans

    const float* pcb = pc + (size_t)b * 3 * NN;
    const float* qcb = qc + (size_t)b * 3 * MM;

    // pass-A query constants: -2*q (4 queries per wave, pair structure)
    float qx2[QPW], qy2[QPW], qz2[QPW];
#pragma unroll
    for (int q = 0; q < QPW; ++q) {
        int m = m0 + pairIdx * QPW + q;
        qx2[q] = -2.0f * qcb[m];
        qy2[q] = -2.0f * qcb[MM + m];
        qz2[q] = -2.0f * qcb[2 * MM + m];
    }

    float mnA[QPW], mnB[QPW];
#pragma unroll
    for (int q = 0; q < QPW; ++q) { mnA[q] = 3.0e38f; mnB[q] = 3.0e38f; }

    // ---------------- pass A: per-lane min of val over 64 points ------------
    for (int c = 0; c < NCHUNK; ++c) {
        __syncthreads();
        STAGE(c);
        __syncthreads();
        const int ob = half * 1024 + lane * 4;
#pragma unroll
        for (int g = 0; g < 4; ++g) {
            int oo = ob + g * 256;
            float4 x4 = *(const float4*)(s_pts + oo);
            float4 y4 = *(const float4*)(s_pts + CHUNK + oo);
            float4 z4 = *(const float4*)(s_pts + 2 * CHUNK + oo);
            float4 p4 = *(const float4*)(s_pts + 3 * CHUNK + oo);
#pragma unroll
            for (int q = 0; q < QPW; ++q) {
                float v0 = VAL(x4.x, y4.x, z4.x, p4.x, qx2[q], qy2[q], qz2[q]);
                float v1 = VAL(x4.y, y4.y, z4.y, p4.y, qx2[q], qy2[q], qz2[q]);
                float v2 = VAL(x4.z, y4.z, z4.z, p4.z, qx2[q], qy2[q], qz2[q]);
                float v3 = VAL(x4.w, y4.w, z4.w, p4.w, qx2[q], qy2[q], qz2[q]);
                mnA[q] = min3f(v0, v1, mnA[q]);
                mnB[q] = min3f(v2, v3, mnB[q]);
            }
        }
    }

    // ---- per-wave radix select: 8th-smallest of 64 lane minima (per query) --
    // coarse: top 16 mapped bits; res|0xFFFF still a provable upper bound
#pragma unroll
    for (int q = 0; q < QPW; ++q) {
        unsigned key = mapf(fminf(mnA[q], mnB[q]));
        unsigned res = 0u;
        for (int bb = 31; bb >= 16; --bb) {
            unsigned cand = res | (1u << bb);
            unsigned long long bal = __ballot(key < cand);
            int c2 = __popcll(bal);
            if (c2 < 8) res = cand;  // 8th smallest has this bit set
        }
        if (lane == 0)
            s_thr[half * QPB + pairIdx * QPW + q] = unmapf(res | 0xFFFFu);
    }
    if (t < QPB) s_cnt[t] = 0;
    __syncthreads();

    // ---- pass-B wave remap: octet of 8 queries x quarter of points ---------
    // t[q] = max(tA8, tB8): >=8 pts <= t in each half => >=16 total => valid
    // upper bound on the true 16th-smallest val.
    const int qo = (wave >> 2) * 8;  // query octet base (4 octets)
    const int qtr = wave & 3;        // point quarter within each chunk
    float qx2b[8], qy2b[8], qz2b[8], thv[8];
#pragma unroll
    for (int q = 0; q < 8; ++q) {
        int m = m0 + qo + q;
        qx2b[q] = -2.0f * qcb[m];  // bit-identical to pass A's constants
        qy2b[q] = -2.0f * qcb[MM + m];
        qz2b[q] = -2.0f * qcb[2 * MM + m];
        thv[q] = fmaxf(s_thr[qo + q], s_thr[QPB + qo + q]);
    }

    // ---------------- pass B: collect survivors val <= t --------------------
    for (int c = 0; c < NCHUNK; ++c) {
        __syncthreads();
        STAGE(c);
        __syncthreads();
        const int ob = qtr * 512 + lane * 4;
#pragma unroll
        for (int g = 0; g < 2; ++g) {
            int oo = ob + g * 256;
            float4 x4 = *(const float4*)(s_pts + oo);
            float4 y4 = *(const float4*)(s_pts + CHUNK + oo);
            float4 z4 = *(const float4*)(s_pts + 2 * CHUNK + oo);
            float4 p4 = *(const float4*)(s_pts + 3 * CHUNK + oo);
            int gi = c * CHUNK + oo;
#pragma unroll
            for (int q = 0; q < 8; ++q) {
                float v0 = VAL(x4.x, y4.x, z4.x, p4.x, qx2b[q], qy2b[q], qz2b[q]);
                float v1 = VAL(x4.y, y4.y, z4.y, p4.y, qx2b[q], qy2b[q], qz2b[q]);
                float v2 = VAL(x4.z, y4.z, z4.z, p4.z, qx2b[q], qy2b[q], qz2b[q]);
                float v3 = VAL(x4.w, y4.w, z4.w, p4.w, qx2b[q], qy2b[q], qz2b[q]);
                // exact whole-group skip: min > t => every element > t
                if (fminf(min3f(v0, v1, v2), v3) <= thv[q]) {
                    int wqq = qo + q;
                    if (v0 <= thv[q]) PUSH(wqq, v0, gi + 0);
                    if (v1 <= thv[q]) PUSH(wqq, v1, gi + 1);
                    if (v2 <= thv[q]) PUSH(wqq, v2, gi + 2);
                    if (v3 <= thv[q]) PUSH(wqq, v3, gi + 3);
                }
            }
        }
    }
    __syncthreads();

    // ------------- exact select: rank survivors by (val, idx) ---------------
#pragma unroll
    for (int qq = 0; qq < 2; ++qq) {
        int wq = wave * 2 + qq;           // 16 waves x 2 = 32 queries
        int cnt = s_cnt[wq];
        cnt = __builtin_amdgcn_readfirstlane(cnt);
        if (cnt > SCAP) cnt = SCAP;
        bool valid = lane < cnt;
        float mv = 0.f;
        int mi = 0;
        if (valid) {
            mv = s_surv[(wq * SCAP + lane) * 2];
            mi = __float_as_int(s_surv[(wq * SCAP + lane) * 2 + 1]);
        }
        int rank = 0;
        for (int j = 0; j < cnt; ++j) {
            float vj = s_surv[(wq * SCAP + j) * 2];
            int ij = __float_as_int(s_surv[(wq * SCAP + j) * 2 + 1]);
            if (valid && (vj < mv || (vj == mv && ij < mi))) rank++;
        }
        if (valid && rank < KK) s_sel[wq * KK + rank] = mi;
    }
    __syncthreads();  // survivors dead; s_surv becomes the output stage

    // -------- softmax + gather, wave-parallel: lane k owns neighbor k -------
    float* stage = s_surv;  // [67 rows][STG=33 cols]
    float tval = temp[0];
    float sigma = fmaxf(tval * tval, 1.0e-4f);
    float inv_sigma = 1.0f / sigma;
    const float* pfTb = pfT + (size_t)b * NN * FF;
    const float* pfb = pf + (size_t)b * FF * NN;

#pragma unroll
    for (int qq = 0; qq < 2; ++qq) {
        int wq = wave * 2 + qq;
        int m = m0 + wq;
        float qxe = qcb[m], qye = qcb[MM + m], qze = qcb[2 * MM + m];
        // every 16-lane group loads the same 16 neighbors (lane&15)
        int ik = s_sel[wq * KK + (lane & 15)];
        float px = pcb[ik], py = pcb[NN + ik], pz = pcb[2 * NN + ik];
        float dx = px - qxe, dy = py - qye, dz = pz - qze;
        float dk = fmaf(dx, dx, fmaf(dy, dy, dz * dz));  // exact direct form
        float dmin = dk;
#pragma unroll
        for (int s = 1; s < 16; s <<= 1) dmin = fminf(dmin, __shfl_xor(dmin, s));
        float e = __expf((dmin - dk) * inv_sigma);
        float ssum = e;
#pragma unroll
        for (int s = 1; s < 16; s <<= 1) ssum += __shfl_xor(ssum, s);
        float w = e * (1.0f / ssum);
        float sx = w * px, sy = w * py, sz = w * pz;
#pragma unroll
        for (int s = 1; s < 16; s <<= 1) {
            sx += __shfl_xor(sx, s);
            sy += __shfl_xor(sy, s);
            sz += __shfl_xor(sz, s);
        }
        // features: all 64 lanes, f = lane; weights broadcast from lanes 0-15
        float facc = 0.f;
#pragma unroll
        for (int k = 0; k < KK; ++k) {
            float wk = __shfl(w, k);
            int iik = __shfl(ik, k);
            float fv = useT ? pfTb[(size_t)iik * FF + lane]
                            : pfb[(size_t)lane * NN + iik];
            facc = fmaf(wk, fv, facc);
        }
        stage[lane * STG + wq] = facc;
        if (lane == 0) {
            stage[(64) * STG + wq] = sx;
            stage[(65) * STG + wq] = sy;
            stage[(66) * STG + wq] = sz;
        }
    }
    __syncthreads();

    // ---------------- coalesced write-out -----------------------------------
    const size_t featOff = (size_t)BB * 3 * MM;
    for (int j = t; j < 67 * QPB; j += NTHR) {
        int row = j >> 5, col = j & 31;
        float v = stage[row * STG + col];
        int m = m0 + col;
        if (row < 64)
            out[featOff + (size_t)b * FF * MM + (size_t)row * MM + m] = v;
        else
            out[(size_t)b * 3 * MM + (size_t)(row - 64) * MM + m] = v;
    }
}

extern "C" void kernel_launch(void* const* d_in, const int* in_sizes, int n_in,
                              void* d_out, int out_size, void* d_ws, size_t ws_size,
                              hipStream_t stream) {
    (void)in_sizes; (void)n_in; (void)out_size;
    const float* pc = (const float*)d_in[0];
    const float* qc = (const float*)d_in[1];
    const float* pf = (const float*)d_in[2];
    const float* temp = (const float*)d_in[3];
    float* out = (float*)d_out;
    float* pfT = (float*)d_ws;
    const size_t needT = (size_t)BB * NN * FF * sizeof(float);  // 8 MB
    int useT = (ws_size >= needT && d_ws != nullptr) ? 1 : 0;

    if (useT) {
        hipLaunchKernelGGL(transpose_feat, dim3(NN / 64, BB), dim3(256), 0, stream,
                           pf, pfT);
    }
    hipLaunchKernelGGL(soft_proj_kernel, dim3((BB * MM) / QPB), dim3(NTHR), 0,
                       stream, pc, qc, pf, pfT, temp, out, useT);
}

// Round 11
// 121.905 us; speedup vs baseline: 1.1240x; 1.1240x over previous
//
#include <hip/hip_runtime.h>

// SoftProjection: B=4, N=8192 points, M=4096 queries, F=64 features, K=16 NN.
// R13: R12's pass-B octet remap, spill-fixed. R12 passed correctness but
// spilled (VGPR pinned 32, WRITE 4.3->35MB, 57->78us): the 32 floats of
// pass-B query state (8q x {qx,qy,qz,thr}) are WAVE-UNIFORM, so R13 forces
// them into SGPRs via readfirstlane (exact on uniform values => VAL chain
// still bit-identical to pass A; v_fma reads <=1 SGPR/instr so zero extra
// VALU). Pass B: wave = (octet wave>>2 -> 8 queries) x (quarter wave&3,
// ob = qtr*512+lane*4): each 64B group-load serves 32 pair-evals (2x R11),
// halving pass-B LDS reads + addressing. Everything else = R11 (validated
// best, 118.9us total / 57.2us main): pass A QPW=4 wave-pairs min3 scan,
// 16-iter radix 8th-per-half, t=max(halves); exact (val,idx) rank;
// wave-parallel exact direct-form d2 epilogue.
// 512 blocks x 1024 thr, LDS 49KB, 2 blocks/CU.

#define BB 4
#define NN 8192
#define MM 4096
#define FF 64
#define KK 16
#define CHUNK 2048
#define NCHUNK 4
#define QPW 4
#define QPB 32
#define SCAP 54
#define NTHR 1024
#define STG 33

__device__ __forceinline__ float min3f(float a, float b, float c) {
    float d;
    asm("v_min3_f32 %0, %1, %2, %3" : "=v"(d) : "v"(a), "v"(b), "v"(c));
    return d;
}
__device__ __forceinline__ float rfl(float x) {  // uniform value -> SGPR
    return __int_as_float(__builtin_amdgcn_readfirstlane(__float_as_int(x)));
}

__global__ __launch_bounds__(256) void transpose_feat(const float* __restrict__ pf,
                                                      float* __restrict__ pfT) {
    __shared__ float tile[64][65];
    const int b = blockIdx.y;
    const int n0 = blockIdx.x * 64;
    const int t = threadIdx.x;
    const int n = t & 63, fq = t >> 6;
#pragma unroll
    for (int i = 0; i < 16; ++i) {
        int f = fq * 16 + i;
        tile[f][n] = pf[(size_t)b * FF * NN + (size_t)f * NN + n0 + n];
    }
    __syncthreads();
    const int f2 = t & 63, nq = t >> 6;
#pragma unroll
    for (int i = 0; i < 16; ++i) {
        int nn2 = nq * 16 + i;
        pfT[(size_t)b * NN * FF + (size_t)(n0 + nn2) * FF + f2] = tile[f2][nn2];
    }
}

__device__ __forceinline__ unsigned mapf(float f) {
    unsigned u = __float_as_uint(f);
    return (u & 0x80000000u) ? ~u : (u | 0x80000000u);
}
__device__ __forceinline__ float unmapf(unsigned k) {
    return (k & 0x80000000u) ? __uint_as_float(k ^ 0x80000000u)
                             : __uint_as_float(~k);
}

// stage chunk C of point cloud into LDS: x, y, z, ps=|p|^2 (512 stager threads)
#define STAGE(C)                                                            \
    do {                                                                    \
        if (t < CHUNK / 4) {                                                \
            int base_ = (C)*CHUNK + t * 4;                                  \
            float4 x4_ = *(const float4*)(pcb + base_);                     \
            float4 y4_ = *(const float4*)(pcb + NN + base_);                \
            float4 z4_ = *(const float4*)(pcb + 2 * NN + base_);            \
            *(float4*)(s_pts + t * 4) = x4_;                                \
            *(float4*)(s_pts + CHUNK + t * 4) = y4_;                        \
            *(float4*)(s_pts + 2 * CHUNK + t * 4) = z4_;                    \
            float4 p4_;                                                     \
            p4_.x = fmaf(x4_.x, x4_.x, fmaf(y4_.x, y4_.x, z4_.x * z4_.x));  \
            p4_.y = fmaf(x4_.y, x4_.y, fmaf(y4_.y, y4_.y, z4_.y * z4_.y));  \
            p4_.z = fmaf(x4_.z, x4_.z, fmaf(y4_.z, y4_.z, z4_.z * z4_.z));  \
            p4_.w = fmaf(x4_.w, x4_.w, fmaf(y4_.w, y4_.w, z4_.w * z4_.w));  \
            *(float4*)(s_pts + 3 * CHUNK + t * 4) = p4_;                    \
        }                                                                   \
    } while (0)

// identical val expression in both passes (explicit fmaf => bit-deterministic)
#define VAL(X, Y, Z, PS, QX, QY, QZ) \
    fmaf((X), (QX), fmaf((Y), (QY), fmaf((Z), (QZ), (PS))))

#define PUSH(WQ, V, I)                                          \
    do {                                                        \
        int pos_ = atomicAdd(&s_cnt[WQ], 1);                    \
        if (pos_ < SCAP) {                                      \
            s_surv[((WQ)*SCAP + pos_) * 2] = (V);               \
            s_surv[((WQ)*SCAP + pos_) * 2 + 1] = __int_as_float(I); \
        }                                                       \
    } while (0)

__global__ __launch_bounds__(NTHR, 8) void soft_proj_kernel(
    const float* __restrict__ pc, const float* __restrict__ qc,
    const float* __restrict__ pf, const float* __restrict__ pfT,
    const float* __restrict__ temp, float* __restrict__ out, int useT) {
    __shared__ __align__(16) float s_pts[4 * CHUNK];        // 32768 B
    __shared__ __align__(16) float s_surv[QPB * SCAP * 2];  // 13824 B (val,idx)
    __shared__ int s_cnt[QPB];                              // 128 B
    __shared__ int s_sel[QPB * KK];                         // 2048 B
    __shared__ float s_thr[2 * QPB];                        // 256 B => 49024 B

    const int bid = blockIdx.x;
    const int b = bid >> 7;               // 128 blocks per batch
    const int m0 = (bid & 127) * QPB;
    const int t = threadIdx.x;
    const int wave = t >> 6;              // 16 waves
    const int lane = t & 63;
    const int pairIdx = wave & 7;         // 8 wave-pairs x QPW=4 queries = 32
    const int half = wave >> 3;           // which point-half this wave scans

    const float* pcb = pc + (size_t)b * 3 * NN;
    const float* qcb = qc + (size_t)b * 3 * MM;

    // pass-A query constants: -2*q (4 queries per wave, pair structure)
    float qx2[QPW], qy2[QPW], qz2[QPW];
#pragma unroll
    for (int q = 0; q < QPW; ++q) {
        int m = m0 + pairIdx * QPW + q;
        qx2[q] = -2.0f * qcb[m];
        qy2[q] = -2.0f * qcb[MM + m];
        qz2[q] = -2.0f * qcb[2 * MM + m];
    }

    float mnA[QPW], mnB[QPW];
#pragma unroll
    for (int q = 0; q < QPW; ++q) { mnA[q] = 3.0e38f; mnB[q] = 3.0e38f; }

    // ---------------- pass A: per-lane min of val over 64 points ------------
    for (int c = 0; c < NCHUNK; ++c) {
        __syncthreads();
        STAGE(c);
        __syncthreads();
        const int ob = half * 1024 + lane * 4;
#pragma unroll
        for (int g = 0; g < 4; ++g) {
            int oo = ob + g * 256;
            float4 x4 = *(const float4*)(s_pts + oo);
            float4 y4 = *(const float4*)(s_pts + CHUNK + oo);
            float4 z4 = *(const float4*)(s_pts + 2 * CHUNK + oo);
            float4 p4 = *(const float4*)(s_pts + 3 * CHUNK + oo);
#pragma unroll
            for (int q = 0; q < QPW; ++q) {
                float v0 = VAL(x4.x, y4.x, z4.x, p4.x, qx2[q], qy2[q], qz2[q]);
                float v1 = VAL(x4.y, y4.y, z4.y, p4.y, qx2[q], qy2[q], qz2[q]);
                float v2 = VAL(x4.z, y4.z, z4.z, p4.z, qx2[q], qy2[q], qz2[q]);
                float v3 = VAL(x4.w, y4.w, z4.w, p4.w, qx2[q], qy2[q], qz2[q]);
                mnA[q] = min3f(v0, v1, mnA[q]);
                mnB[q] = min3f(v2, v3, mnB[q]);
            }
        }
    }

    // ---- per-wave radix select: 8th-smallest of 64 lane minima (per query) --
    // coarse: top 16 mapped bits; res|0xFFFF still a provable upper bound
#pragma unroll
    for (int q = 0; q < QPW; ++q) {
        unsigned key = mapf(fminf(mnA[q], mnB[q]));
        unsigned res = 0u;
        for (int bb = 31; bb >= 16; --bb) {
            unsigned cand = res | (1u << bb);
            unsigned long long bal = __ballot(key < cand);
            int c2 = __popcll(bal);
            if (c2 < 8) res = cand;  // 8th smallest has this bit set
        }
        if (lane == 0)
            s_thr[half * QPB + pairIdx * QPW + q] = unmapf(res | 0xFFFFu);
    }
    if (t < QPB) s_cnt[t] = 0;
    __syncthreads();

    // ---- pass-B wave remap: octet of 8 queries x quarter of points ---------
    // t[q] = max(tA8, tB8): >=8 pts <= t in each half => >=16 total => valid
    // upper bound. All 8q x {qx,qy,qz,thr} are wave-uniform -> SGPRs (rfl is
    // exact on uniform values; -2.0f*q recomputed identically to pass A).
    const int qo = (wave >> 2) * 8;  // query octet base (4 octets)
    const int qtr = wave & 3;        // point quarter within each chunk
    float qx2b[8], qy2b[8], qz2b[8], thv[8];
#pragma unroll
    for (int q = 0; q < 8; ++q) {
        int m = m0 + qo + q;
        qx2b[q] = rfl(-2.0f * qcb[m]);
        qy2b[q] = rfl(-2.0f * qcb[MM + m]);
        qz2b[q] = rfl(-2.0f * qcb[2 * MM + m]);
        thv[q] = rfl(fmaxf(s_thr[qo + q], s_thr[QPB + qo + q]));
    }

    // ---------------- pass B: collect survivors val <= t --------------------
    for (int c = 0; c < NCHUNK; ++c) {
        __syncthreads();
        STAGE(c);
        __syncthreads();
        const int ob = qtr * 512 + lane * 4;
#pragma unroll
        for (int g = 0; g < 2; ++g) {
            int oo = ob + g * 256;
            float4 x4 = *(const float4*)(s_pts + oo);
            float4 y4 = *(const float4*)(s_pts + CHUNK + oo);
            float4 z4 = *(const float4*)(s_pts + 2 * CHUNK + oo);
            float4 p4 = *(const float4*)(s_pts + 3 * CHUNK + oo);
            int gi = c * CHUNK + oo;
#pragma unroll
            for (int q = 0; q < 8; ++q) {
                float v0 = VAL(x4.x, y4.x, z4.x, p4.x, qx2b[q], qy2b[q], qz2b[q]);
                float v1 = VAL(x4.y, y4.y, z4.y, p4.y, qx2b[q], qy2b[q], qz2b[q]);
                float v2 = VAL(x4.z, y4.z, z4.z, p4.z, qx2b[q], qy2b[q], qz2b[q]);
                float v3 = VAL(x4.w, y4.w, z4.w, p4.w, qx2b[q], qy2b[q], qz2b[q]);
                // exact whole-group skip: min > t => every element > t
                if (fminf(min3f(v0, v1, v2), v3) <= thv[q]) {
                    int wqq = qo + q;
                    if (v0 <= thv[q]) PUSH(wqq, v0, gi + 0);
                    if (v1 <= thv[q]) PUSH(wqq, v1, gi + 1);
                    if (v2 <= thv[q]) PUSH(wqq, v2, gi + 2);
                    if (v3 <= thv[q]) PUSH(wqq, v3, gi + 3);
                }
            }
        }
    }
    __syncthreads();

    // ------------- exact select: rank survivors by (val, idx) ---------------
#pragma unroll
    for (int qq = 0; qq < 2; ++qq) {
        int wq = wave * 2 + qq;           // 16 waves x 2 = 32 queries
        int cnt = s_cnt[wq];
        cnt = __builtin_amdgcn_readfirstlane(cnt);
        if (cnt > SCAP) cnt = SCAP;
        bool valid = lane < cnt;
        float mv = 0.f;
        int mi = 0;
        if (valid) {
            mv = s_surv[(wq * SCAP + lane) * 2];
            mi = __float_as_int(s_surv[(wq * SCAP + lane) * 2 + 1]);
        }
        int rank = 0;
        for (int j = 0; j < cnt; ++j) {
            float vj = s_surv[(wq * SCAP + j) * 2];
            int ij = __float_as_int(s_surv[(wq * SCAP + j) * 2 + 1]);
            if (valid && (vj < mv || (vj == mv && ij < mi))) rank++;
        }
        if (valid && rank < KK) s_sel[wq * KK + rank] = mi;
    }
    __syncthreads();  // survivors dead; s_surv becomes the output stage

    // -------- softmax + gather, wave-parallel: lane k owns neighbor k -------
    float* stage = s_surv;  // [67 rows][STG=33 cols]
    float tval = temp[0];
    float sigma = fmaxf(tval * tval, 1.0e-4f);
    float inv_sigma = 1.0f / sigma;
    const float* pfTb = pfT + (size_t)b * NN * FF;
    const float* pfb = pf + (size_t)b * FF * NN;

#pragma unroll
    for (int qq = 0; qq < 2; ++qq) {
        int wq = wave * 2 + qq;
        int m = m0 + wq;
        float qxe = qcb[m], qye = qcb[MM + m], qze = qcb[2 * MM + m];
        // every 16-lane group loads the same 16 neighbors (lane&15)
        int ik = s_sel[wq * KK + (lane & 15)];
        float px = pcb[ik], py = pcb[NN + ik], pz = pcb[2 * NN + ik];
        float dx = px - qxe, dy = py - qye, dz = pz - qze;
        float dk = fmaf(dx, dx, fmaf(dy, dy, dz * dz));  // exact direct form
        float dmin = dk;
#pragma unroll
        for (int s = 1; s < 16; s <<= 1) dmin = fminf(dmin, __shfl_xor(dmin, s));
        float e = __expf((dmin - dk) * inv_sigma);
        float ssum = e;
#pragma unroll
        for (int s = 1; s < 16; s <<= 1) ssum += __shfl_xor(ssum, s);
        float w = e * (1.0f / ssum);
        float sx = w * px, sy = w * py, sz = w * pz;
#pragma unroll
        for (int s = 1; s < 16; s <<= 1) {
            sx += __shfl_xor(sx, s);
            sy += __shfl_xor(sy, s);
            sz += __shfl_xor(sz, s);
        }
        // features: all 64 lanes, f = lane; weights broadcast from lanes 0-15
        float facc = 0.f;
#pragma unroll
        for (int k = 0; k < KK; ++k) {
            float wk = __shfl(w, k);
            int iik = __shfl(ik, k);
            float fv = useT ? pfTb[(size_t)iik * FF + lane]
                            : pfb[(size_t)lane * NN + iik];
            facc = fmaf(wk, fv, facc);
        }
        stage[lane * STG + wq] = facc;
        if (lane == 0) {
            stage[(64) * STG + wq] = sx;
            stage[(65) * STG + wq] = sy;
            stage[(66) * STG + wq] = sz;
        }
    }
    __syncthreads();

    // ---------------- coalesced write-out -----------------------------------
    const size_t featOff = (size_t)BB * 3 * MM;
    for (int j = t; j < 67 * QPB; j += NTHR) {
        int row = j >> 5, col = j & 31;
        float v = stage[row * STG + col];
        int m = m0 + col;
        if (row < 64)
            out[featOff + (size_t)b * FF * MM + (size_t)row * MM + m] = v;
        else
            out[(size_t)b * 3 * MM + (size_t)(row - 64) * MM + m] = v;
    }
}

extern "C" void kernel_launch(void* const* d_in, const int* in_sizes, int n_in,
                              void* d_out, int out_size, void* d_ws, size_t ws_size,
                              hipStream_t stream) {
    (void)in_sizes; (void)n_in; (void)out_size;
    const float* pc = (const float*)d_in[0];
    const float* qc = (const float*)d_in[1];
    const float* pf = (const float*)d_in[2];
    const float* temp = (const float*)d_in[3];
    float* out = (float*)d_out;
    float* pfT = (float*)d_ws;
    const size_t needT = (size_t)BB * NN * FF * sizeof(float);  // 8 MB
    int useT = (ws_size >= needT && d_ws != nullptr) ? 1 : 0;

    if (useT) {
        hipLaunchKernelGGL(transpose_feat, dim3(NN / 64, BB), dim3(256), 0, stream,
                           pf, pfT);
    }
    hipLaunchKernelGGL(soft_proj_kernel, dim3((BB * MM) / QPB), dim3(NTHR), 0,
                       stream, pc, qc, pf, pfT, temp, out, useT);
}

// Round 12
// 119.290 us; speedup vs baseline: 1.1486x; 1.0219x over previous
//
#include <hip/hip_runtime.h>

// SoftProjection: B=4, N=8192 points, M=4096 queries, F=64 features, K=16 NN.
// R14: R11 (validated best: 118.9us total / 57.2us main) + big-chunk staging.
// R12/R13's pass-B query-sharing lever is abandoned (both spilled: WRITE
// 4.3->35/12.5MB; the allocator won't hold 8-query state at this occupancy).
// R11's isolated inefficiency: during each STAGE phase only 512/1024 threads
// work (8 phases x 2 barriers, half the waves idle). Fix: CHUNK 2048->4096,
// NCHUNK 4->2 -- all 1024 threads stage (same 4 pts/thread), stage wall time
// ~halves, barrier phases 16->8. s_pts grows to 64KB; s_sel (2KB) aliases
// into s_pts (dead after pass B's last read; s_sel first written after the
// post-B barrier) => LDS 79744B/block, 2 blocks/CU preserved (159.5KB<160KB).
// All validated machinery byte-identical to R11: pass A QPW=4 wave-pair min3
// scan; 16-iter radix 8th-smallest per half, t=max(halves) => >=16 pts <= t;
// pass B half-split survivor collect (guard min3, SCAP 54); exact (val,idx)
// rank; wave-parallel exact direct-form d2 epilogue.
// 512 blocks x 1024 thr.

#define BB 4
#define NN 8192
#define MM 4096
#define FF 64
#define KK 16
#define CHUNK 4096
#define NCHUNK 2
#define QPW 4
#define QPB 32
#define SCAP 54
#define NTHR 1024
#define STG 33

__device__ __forceinline__ float min3f(float a, float b, float c) {
    float d;
    asm("v_min3_f32 %0, %1, %2, %3" : "=v"(d) : "v"(a), "v"(b), "v"(c));
    return d;
}

__global__ __launch_bounds__(256) void transpose_feat(const float* __restrict__ pf,
                                                      float* __restrict__ pfT) {
    __shared__ float tile[64][65];
    const int b = blockIdx.y;
    const int n0 = blockIdx.x * 64;
    const int t = threadIdx.x;
    const int n = t & 63, fq = t >> 6;
#pragma unroll
    for (int i = 0; i < 16; ++i) {
        int f = fq * 16 + i;
        tile[f][n] = pf[(size_t)b * FF * NN + (size_t)f * NN + n0 + n];
    }
    __syncthreads();
    const int f2 = t & 63, nq = t >> 6;
#pragma unroll
    for (int i = 0; i < 16; ++i) {
        int nn2 = nq * 16 + i;
        pfT[(size_t)b * NN * FF + (size_t)(n0 + nn2) * FF + f2] = tile[f2][nn2];
    }
}

__device__ __forceinline__ unsigned mapf(float f) {
    unsigned u = __float_as_uint(f);
    return (u & 0x80000000u) ? ~u : (u | 0x80000000u);
}
__device__ __forceinline__ float unmapf(unsigned k) {
    return (k & 0x80000000u) ? __uint_as_float(k ^ 0x80000000u)
                             : __uint_as_float(~k);
}

// stage chunk C of point cloud into LDS: x, y, z, ps=|p|^2 (ALL 1024 threads)
#define STAGE(C)                                                            \
    do {                                                                    \
        int base_ = (C)*CHUNK + t * 4;                                      \
        float4 x4_ = *(const float4*)(pcb + base_);                         \
        float4 y4_ = *(const float4*)(pcb + NN + base_);                    \
        float4 z4_ = *(const float4*)(pcb + 2 * NN + base_);                \
        *(float4*)(s_pts + t * 4) = x4_;                                    \
        *(float4*)(s_pts + CHUNK + t * 4) = y4_;                            \
        *(float4*)(s_pts + 2 * CHUNK + t * 4) = z4_;                        \
        float4 p4_;                                                         \
        p4_.x = fmaf(x4_.x, x4_.x, fmaf(y4_.x, y4_.x, z4_.x * z4_.x));      \
        p4_.y = fmaf(x4_.y, x4_.y, fmaf(y4_.y, y4_.y, z4_.y * z4_.y));      \
        p4_.z = fmaf(x4_.z, x4_.z, fmaf(y4_.z, y4_.z, z4_.z * z4_.z));      \
        p4_.w = fmaf(x4_.w, x4_.w, fmaf(y4_.w, y4_.w, z4_.w * z4_.w));      \
        *(float4*)(s_pts + 3 * CHUNK + t * 4) = p4_;                        \
    } while (0)

// identical val expression in both passes (explicit fmaf => bit-deterministic)
#define VAL(X, Y, Z, PS, QX, QY, QZ) \
    fmaf((X), (QX), fmaf((Y), (QY), fmaf((Z), (QZ), (PS))))

#define PUSH(WQ, V, I)                                          \
    do {                                                        \
        int pos_ = atomicAdd(&s_cnt[WQ], 1);                    \
        if (pos_ < SCAP) {                                      \
            s_surv[((WQ)*SCAP + pos_) * 2] = (V);               \
            s_surv[((WQ)*SCAP + pos_) * 2 + 1] = __int_as_float(I); \
        }                                                       \
    } while (0)

__global__ __launch_bounds__(NTHR, 8) void soft_proj_kernel(
    const float* __restrict__ pc, const float* __restrict__ qc,
    const float* __restrict__ pf, const float* __restrict__ pfT,
    const float* __restrict__ temp, float* __restrict__ out, int useT) {
    __shared__ __align__(16) float s_pts[4 * CHUNK];        // 65536 B
    __shared__ __align__(16) float s_surv[QPB * SCAP * 2];  // 13824 B (val,idx)
    __shared__ int s_cnt[QPB];                              // 128 B
    __shared__ float s_thr[2 * QPB];                        // 256 B => 79744 B
    int* s_sel = (int*)s_pts;  // [QPB*KK] aliases s_pts (dead after pass B)

    const int bid = blockIdx.x;
    const int b = bid >> 7;               // 128 blocks per batch
    const int m0 = (bid & 127) * QPB;
    const int t = threadIdx.x;
    const int wave = t >> 6;              // 16 waves
    const int lane = t & 63;
    const int pairIdx = wave & 7;         // 8 wave-pairs x QPW=4 queries = 32
    const int half = wave >> 3;           // which point-half this wave scans

    const float* pcb = pc + (size_t)b * 3 * NN;
    const float* qcb = qc + (size_t)b * 3 * MM;

    // scan-phase query constants: -2*q
    float qx2[QPW], qy2[QPW], qz2[QPW];
#pragma unroll
    for (int q = 0; q < QPW; ++q) {
        int m = m0 + pairIdx * QPW + q;
        qx2[q] = -2.0f * qcb[m];
        qy2[q] = -2.0f * qcb[MM + m];
        qz2[q] = -2.0f * qcb[2 * MM + m];
    }

    float mnA[QPW], mnB[QPW];
#pragma unroll
    for (int q = 0; q < QPW; ++q) { mnA[q] = 3.0e38f; mnB[q] = 3.0e38f; }

    // ---------------- pass A: per-lane min of val over 128 points -----------
    for (int c = 0; c < NCHUNK; ++c) {
        __syncthreads();
        STAGE(c);
        __syncthreads();
        const int ob = half * 2048 + lane * 4;
#pragma unroll
        for (int g = 0; g < 8; ++g) {
            int oo = ob + g * 256;
            float4 x4 = *(const float4*)(s_pts + oo);
            float4 y4 = *(const float4*)(s_pts + CHUNK + oo);
            float4 z4 = *(const float4*)(s_pts + 2 * CHUNK + oo);
            float4 p4 = *(const float4*)(s_pts + 3 * CHUNK + oo);
#pragma unroll
            for (int q = 0; q < QPW; ++q) {
                float v0 = VAL(x4.x, y4.x, z4.x, p4.x, qx2[q], qy2[q], qz2[q]);
                float v1 = VAL(x4.y, y4.y, z4.y, p4.y, qx2[q], qy2[q], qz2[q]);
                float v2 = VAL(x4.z, y4.z, z4.z, p4.z, qx2[q], qy2[q], qz2[q]);
                float v3 = VAL(x4.w, y4.w, z4.w, p4.w, qx2[q], qy2[q], qz2[q]);
                mnA[q] = min3f(v0, v1, mnA[q]);
                mnB[q] = min3f(v2, v3, mnB[q]);
            }
        }
    }

    // ---- per-wave radix select: 8th-smallest of 64 lane minima (per query) --
    // coarse: top 16 mapped bits; res|0xFFFF still a provable upper bound
#pragma unroll
    for (int q = 0; q < QPW; ++q) {
        unsigned key = mapf(fminf(mnA[q], mnB[q]));
        unsigned res = 0u;
        for (int bb = 31; bb >= 16; --bb) {
            unsigned cand = res | (1u << bb);
            unsigned long long bal = __ballot(key < cand);
            int c2 = __popcll(bal);
            if (c2 < 8) res = cand;  // 8th smallest has this bit set
        }
        if (lane == 0)
            s_thr[half * QPB + pairIdx * QPW + q] = unmapf(res | 0xFFFFu);
    }
    if (t < QPB) s_cnt[t] = 0;
    __syncthreads();
    // t = max(tA8, tB8): >=8 points <= t in each half => >=16 total => valid
    // upper bound on the true 16th-smallest val.
    float thv[QPW];
#pragma unroll
    for (int q = 0; q < QPW; ++q)
        thv[q] = fmaxf(s_thr[pairIdx * QPW + q], s_thr[QPB + pairIdx * QPW + q]);

    // ---------------- pass B: collect survivors val <= t --------------------
    for (int c = 0; c < NCHUNK; ++c) {
        __syncthreads();
        STAGE(c);
        __syncthreads();
        const int ob = half * 2048 + lane * 4;
#pragma unroll
        for (int g = 0; g < 8; ++g) {
            int oo = ob + g * 256;
            float4 x4 = *(const float4*)(s_pts + oo);
            float4 y4 = *(const float4*)(s_pts + CHUNK + oo);
            float4 z4 = *(const float4*)(s_pts + 2 * CHUNK + oo);
            float4 p4 = *(const float4*)(s_pts + 3 * CHUNK + oo);
            int gi = c * CHUNK + oo;
#pragma unroll
            for (int q = 0; q < QPW; ++q) {
                float v0 = VAL(x4.x, y4.x, z4.x, p4.x, qx2[q], qy2[q], qz2[q]);
                float v1 = VAL(x4.y, y4.y, z4.y, p4.y, qx2[q], qy2[q], qz2[q]);
                float v2 = VAL(x4.z, y4.z, z4.z, p4.z, qx2[q], qy2[q], qz2[q]);
                float v3 = VAL(x4.w, y4.w, z4.w, p4.w, qx2[q], qy2[q], qz2[q]);
                // exact whole-group skip: min > t => every element > t
                if (fminf(min3f(v0, v1, v2), v3) <= thv[q]) {
                    int wqq = pairIdx * QPW + q;
                    if (v0 <= thv[q]) PUSH(wqq, v0, gi + 0);
                    if (v1 <= thv[q]) PUSH(wqq, v1, gi + 1);
                    if (v2 <= thv[q]) PUSH(wqq, v2, gi + 2);
                    if (v3 <= thv[q]) PUSH(wqq, v3, gi + 3);
                }
            }
        }
    }
    __syncthreads();  // s_pts dead from here; s_sel (alias) becomes live

    // ------------- exact select: rank survivors by (val, idx) ---------------
#pragma unroll
    for (int qq = 0; qq < 2; ++qq) {
        int wq = wave * 2 + qq;           // 16 waves x 2 = 32 queries
        int cnt = s_cnt[wq];
        cnt = __builtin_amdgcn_readfirstlane(cnt);
        if (cnt > SCAP) cnt = SCAP;
        bool valid = lane < cnt;
        float mv = 0.f;
        int mi = 0;
        if (valid) {
            mv = s_surv[(wq * SCAP + lane) * 2];
            mi = __float_as_int(s_surv[(wq * SCAP + lane) * 2 + 1]);
        }
        int rank = 0;
        for (int j = 0; j < cnt; ++j) {
            float vj = s_surv[(wq * SCAP + j) * 2];
            int ij = __float_as_int(s_surv[(wq * SCAP + j) * 2 + 1]);
            if (valid && (vj < mv || (vj == mv && ij < mi))) rank++;
        }
        if (valid && rank < KK) s_sel[wq * KK + rank] = mi;
    }
    __syncthreads();  // survivors dead; s_surv becomes the output stage

    // -------- softmax + gather, wave-parallel: lane k owns neighbor k -------
    float* stage = s_surv;  // [67 rows][STG=33 cols]
    float tval = temp[0];
    float sigma = fmaxf(tval * tval, 1.0e-4f);
    float inv_sigma = 1.0f / sigma;
    const float* pfTb = pfT + (size_t)b * NN * FF;
    const float* pfb = pf + (size_t)b * FF * NN;

#pragma unroll
    for (int qq = 0; qq < 2; ++qq) {
        int wq = wave * 2 + qq;
        int m = m0 + wq;
        float qxe = qcb[m], qye = qcb[MM + m], qze = qcb[2 * MM + m];
        // every 16-lane group loads the same 16 neighbors (lane&15)
        int ik = s_sel[wq * KK + (lane & 15)];
        float px = pcb[ik], py = pcb[NN + ik], pz = pcb[2 * NN + ik];
        float dx = px - qxe, dy = py - qye, dz = pz - qze;
        float dk = fmaf(dx, dx, fmaf(dy, dy, dz * dz));  // exact direct form
        float dmin = dk;
#pragma unroll
        for (int s = 1; s < 16; s <<= 1) dmin = fminf(dmin, __shfl_xor(dmin, s));
        float e = __expf((dmin - dk) * inv_sigma);
        float ssum = e;
#pragma unroll
        for (int s = 1; s < 16; s <<= 1) ssum += __shfl_xor(ssum, s);
        float w = e * (1.0f / ssum);
        float sx = w * px, sy = w * py, sz = w * pz;
#pragma unroll
        for (int s = 1; s < 16; s <<= 1) {
            sx += __shfl_xor(sx, s);
            sy += __shfl_xor(sy, s);
            sz += __shfl_xor(sz, s);
        }
        // features: all 64 lanes, f = lane; weights broadcast from lanes 0-15
        float facc = 0.f;
#pragma unroll
        for (int k = 0; k < KK; ++k) {
            float wk = __shfl(w, k);
            int iik = __shfl(ik, k);
            float fv = useT ? pfTb[(size_t)iik * FF + lane]
                            : pfb[(size_t)lane * NN + iik];
            facc = fmaf(wk, fv, facc);
        }
        stage[lane * STG + wq] = facc;
        if (lane == 0) {
            stage[(64) * STG + wq] = sx;
            stage[(65) * STG + wq] = sy;
            stage[(66) * STG + wq] = sz;
        }
    }
    __syncthreads();

    // ---------------- coalesced write-out -----------------------------------
    const size_t featOff = (size_t)BB * 3 * MM;
    for (int j = t; j < 67 * QPB; j += NTHR) {
        int row = j >> 5, col = j & 31;
        float v = stage[row * STG + col];
        int m = m0 + col;
        if (row < 64)
            out[featOff + (size_t)b * FF * MM + (size_t)row * MM + m] = v;
        else
            out[(size_t)b * 3 * MM + (size_t)(row - 64) * MM + m] = v;
    }
}

extern "C" void kernel_launch(void* const* d_in, const int* in_sizes, int n_in,
                              void* d_out, int out_size, void* d_ws, size_t ws_size,
                              hipStream_t stream) {
    (void)in_sizes; (void)n_in; (void)out_size;
    const float* pc = (const float*)d_in[0];
    const float* qc = (const float*)d_in[1];
    const float* pf = (const float*)d_in[2];
    const float* temp = (const float*)d_in[3];
    float* out = (float*)d_out;
    float* pfT = (float*)d_ws;
    const size_t needT = (size_t)BB * NN * FF * sizeof(float);  // 8 MB
    int useT = (ws_size >= needT && d_ws != nullptr) ? 1 : 0;

    if (useT) {
        hipLaunchKernelGGL(transpose_feat, dim3(NN / 64, BB), dim3(256), 0, stream,
                           pf, pfT);
    }
    hipLaunchKernelGGL(soft_proj_kernel, dim3((BB * MM) / QPB), dim3(NTHR), 0,
                       stream, pc, qc, pf, pfT, temp, out, useT);
}